// Round 1
// baseline (141.423 us; speedup 1.0000x reference)
//
#include <hip/hip_runtime.h>
#include <hip/hip_bf16.h>
#include <math.h>

// Problem constants
#define NB   16      // batch
#define CC   64      // channels
#define ICH  32      // inter channels
#define TV   1600    // T*V = 64*25
#define NTV  (NB*TV) // 25600

typedef __bf16 bf16x8 __attribute__((ext_vector_type(8)));
typedef __bf16 bf16x4 __attribute__((ext_vector_type(4)));
typedef float  f32x4  __attribute__((ext_vector_type(4)));

// ---------------------------------------------------------------------------
// K1: 1x1 conv projections, p-split (12-way: 3 proj x 4 o-groups), XCD-
// SWIZZLED so all 12 blocks sharing an x-tile land on ONE XCD residue class
// (x tile then served 12x from that XCD's L2 instead of re-fetched by 8
// XCDs). Proj blocks 0..1247 (48 no-op), gate blocks 1248..1311.
//  Qb = k_x [N,TV,32] (PRE-SCALED by log2e -> attn uses v_exp_f32 directly)
//  Kb = q_x [N,TV,32]   VTb = v_x^T [N,32,TV]
// ---------------------------------------------------------------------------
__global__ __launch_bounds__(256) void proj_gate_kernel(
    const float* __restrict__ x,
    const float* __restrict__ Wv, const float* __restrict__ bv,
    const float* __restrict__ Wk, const float* __restrict__ bk,
    const float* __restrict__ Wq, const float* __restrict__ bq,
    __bf16* __restrict__ Qb, __bf16* __restrict__ Kb,
    __bf16* __restrict__ VTb, float* __restrict__ AVG) {
  if (blockIdx.x >= 1248) {
    // ---- ChannelGate phase 1: per-(n, c) mean over TV ----
    int b = blockIdx.x - 1248;
    int n = b >> 2, cq = b & 3;
    int c16 = threadIdx.x >> 4, l = threadIdx.x & 15;
    int c = cq * 16 + c16;
    const float4* xp = (const float4*)(x + ((size_t)n * CC + c) * TV) + l;
    float s = 0.f;
#pragma unroll
    for (int i = 0; i < 25; ++i) {
      float4 v = xp[i * 16];
      s += v.x + v.y + v.z + v.w;
    }
#pragma unroll
    for (int off = 8; off >= 1; off >>= 1) s += __shfl_down(s, off, 16);
    if (l == 0) AVG[n * CC + c] = s * (1.0f / (float)TV);
    return;
  }

  // XCD swizzle: XCD = blockIdx % 8; tile = r + 8g so all subs of a tile
  // share residue r -> same XCD.
  int r = blockIdx.x & 7;
  int i = blockIdx.x >> 3;               // 0..155
  int g = i / 12, sub = i % 12;          // sub = p*4 + og
  int tile = r + 8 * g;
  if (tile >= 100) return;               // 48 no-op blocks

  int p = sub >> 2, og = sub & 3;
  int ob = og * 8;
  int tvIdx = tile * 256 + threadIdx.x;  // 0..25599
  int n = tvIdx / TV, tv = tvIdx % TV;

  const float* W; const float* B;
  if (p == 0)      { W = Wv; B = bv; }
  else if (p == 1) { W = Wk; B = bk; }
  else             { W = Wq; B = bq; }

  float acc[8];
#pragma unroll
  for (int j = 0; j < 8; ++j) acc[j] = B[ob + j];

  const float* xp = x + (size_t)n * CC * TV + tv;
#pragma unroll 16
  for (int c = 0; c < CC; ++c) {
    float xc = xp[c * TV];
#pragma unroll
    for (int j = 0; j < 8; ++j)
      acc[j] = fmaf(W[(ob + j) * CC + c], xc, acc[j]);
  }

  if (p == 0) {                           // v_x -> transposed
#pragma unroll
    for (int j = 0; j < 8; ++j)
      VTb[(n * ICH + ob + j) * TV + tv] = (__bf16)acc[j];
  } else {
    if (p == 1) {                         // fold log2(e) into k_x: attention
#pragma unroll                            // scores become log2-domain, so the
      for (int j = 0; j < 8; ++j)         // attn kernel uses raw v_exp_f32
        acc[j] *= 1.4426950408889634f;
    }
    bf16x8 t;
#pragma unroll
    for (int j = 0; j < 8; ++j) t[j] = (__bf16)acc[j];
    int base = (n * TV + tv) * ICH + ob;
    if (p == 1) *(bf16x8*)(Qb + base) = t;   // k_x -> attention rows
    else        *(bf16x8*)(Kb + base) = t;   // q_x -> attention cols
  }
}

// ---------------------------------------------------------------------------
// K2: MFMA flash attention (bf16, 2 m-tiles/wave, XCD swizzle, K+V register
// pipelining) + fused BN-stats epilogue with 4-way parallel merge.
// QK^T computed SWAPPED (mfma(K,Q) -> P^T in C-regs): lane (q,m) holds 4
// CONSECUTIVE s-values of attention row m -> packed ds_write_b64 into the
// [row][s] Pbuf (replaces 32 scalar b16 writes/chunk with 8 b64 writes).
// PV reads (ds_read_b128 of Pw[m*72+k]) unchanged. exp via v_exp_f32
// (log2e pre-folded into Qb). Wave chunk imbalance (7 vs 6) rotated per
// block. LDS 31,744 B. Per-block partials to private GSP slot (no atomics).
// Grid = NB*50 = 800.
// ---------------------------------------------------------------------------
__global__ __launch_bounds__(256) void attn_kernel(
    const __bf16* __restrict__ Qb, const __bf16* __restrict__ Kb,
    const __bf16* __restrict__ VTb, __bf16* __restrict__ P,
    const float* __restrict__ Wt, const float* __restrict__ bt,
    float* __restrict__ GSP) {
  __shared__ float smem_f[7936];             // 31,744 B union arena
  int b = blockIdx.x;
  int r8 = b & 7, qq = b >> 3;               // qq in [0,100)
  int n = r8 * 2 + (qq >= 50 ? 1 : 0);
  int rowTile = (qq >= 50) ? qq - 50 : qq;
  int row0 = rowTile * 32;

  int w = threadIdx.x >> 6;
  int lane = threadIdx.x & 63;
  int m = lane & 15, q = lane >> 4;

  // main-loop Pbuf: per wave 2 tiles x 16 x 72 bf16 = 2304 elem (4608 B)
  __bf16* Pw = (__bf16*)smem_f + w * 2304;

  const __bf16* Qn = Qb  + (size_t)n * TV * ICH;
  const __bf16* Kn = Kb  + (size_t)n * TV * ICH;
  const __bf16* Vn = VTb + (size_t)n * ICH * TV;

  bf16x8 aQ0 = *(const bf16x8*)(Qn + (row0 + m) * ICH + q * 8);
  bf16x8 aQ1 = *(const bf16x8*)(Qn + (row0 + 16 + m) * ICH + q * 8);

  f32x4 o00 = {0.f,0.f,0.f,0.f}, o01 = {0.f,0.f,0.f,0.f};
  f32x4 o10 = {0.f,0.f,0.f,0.f}, o11 = {0.f,0.f,0.f,0.f};
  float ls0 = 0.f, ls1 = 0.f;                // lane-local rowsum (row = m)
  const f32x4 zero = {0.f,0.f,0.f,0.f};

  // chunk offset for this wave, rotated per block so the extra (7th) chunk
  // (offset 0) moves between waves across blocks.
  int ow = (w + b) & 3;                      // offset residue; 0 -> 7 chunks
  int nch = (ow == 0) ? 7 : 6;

  // preload chunk 0's K fragments into registers
  bf16x8 bKc[4];
  {
    int s0 = ow * 64;
#pragma unroll
    for (int st = 0; st < 4; ++st)
      bKc[st] = *(const bf16x8*)(Kn + (s0 + st * 16 + m) * ICH + q * 8);
  }

  for (int j = 0; j < nch; ++j) {
    int s0 = (4 * j + ow) * 64;
    // ---- swapped QK^T: C = P^T tile, lane (q,m): col=m (attn row),
    //      rows = s-offset st*16 + q*4 + r (4 consecutive s per lane) ----
#pragma unroll
    for (int st = 0; st < 4; ++st) {
      f32x4 a0 = __builtin_amdgcn_mfma_f32_16x16x32_bf16(bKc[st], aQ0, zero, 0, 0, 0);
      f32x4 a1 = __builtin_amdgcn_mfma_f32_16x16x32_bf16(bKc[st], aQ1, zero, 0, 0, 0);
      bf16x4 t0, t1;
#pragma unroll
      for (int r = 0; r < 4; ++r) {
        float e0 = __builtin_amdgcn_exp2f(a0[r]); ls0 += e0; t0[r] = (__bf16)e0;
        float e1 = __builtin_amdgcn_exp2f(a1[r]); ls1 += e1; t1[r] = (__bf16)e1;
      }
      int off = m * 72 + st * 16 + q * 4;    // byte off m*144+st*32+q*8: 8B-aligned
      *(bf16x4*)(Pw + off)        = t0;      // one ds_write_b64 per st/tile
      *(bf16x4*)(Pw + 1152 + off) = t1;
    }
    // prefetch next chunk's K + this chunk's V BEFORE the wait
    int chn = 4 * (j + 1) + ow;
    int s0n = (chn < 25 ? chn : 0) * 64;       // clamped, wave-uniform
    bf16x8 bKn[4], pV[2][2];
#pragma unroll
    for (int st = 0; st < 4; ++st)
      bKn[st] = *(const bf16x8*)(Kn + (s0n + st * 16 + m) * ICH + q * 8);
#pragma unroll
    for (int kc = 0; kc < 2; ++kc)
#pragma unroll
      for (int ict = 0; ict < 2; ++ict)
        pV[kc][ict] = *(const bf16x8*)(Vn + (ict * 16 + m) * TV + s0 + kc * 32 + q * 8);
    // in-wave DS write->read ordering
    asm volatile("s_waitcnt lgkmcnt(0)" ::: "memory");
    // ---- P*V: 2 k-chunks of 32 s ----
#pragma unroll
    for (int kc = 0; kc < 2; ++kc) {
      bf16x8 aP0 = *(const bf16x8*)(Pw + m * 72 + kc * 32 + q * 8);
      bf16x8 aP1 = *(const bf16x8*)(Pw + 1152 + m * 72 + kc * 32 + q * 8);
      o00 = __builtin_amdgcn_mfma_f32_16x16x32_bf16(aP0, pV[kc][0], o00, 0, 0, 0);
      o10 = __builtin_amdgcn_mfma_f32_16x16x32_bf16(aP1, pV[kc][0], o10, 0, 0, 0);
      o01 = __builtin_amdgcn_mfma_f32_16x16x32_bf16(aP0, pV[kc][1], o01, 0, 0, 0);
      o11 = __builtin_amdgcn_mfma_f32_16x16x32_bf16(aP1, pV[kc][1], o11, 0, 0, 0);
    }
#pragma unroll
    for (int st = 0; st < 4; ++st) bKc[st] = bKn[st];
  }

  // row sums: lane (q,m) has the partial for row m over its q-subset of s;
  // sum the 4 q-lanes, then gather into the merge layout (row = q*4+r).
  ls0 += __shfl_xor(ls0, 16, 64); ls0 += __shfl_xor(ls0, 32, 64);
  ls1 += __shfl_xor(ls1, 16, 64); ls1 += __shfl_xor(ls1, 32, 64);
  f32x4 lv0, lv1;
#pragma unroll
  for (int r = 0; r < 4; ++r) {
    int src = q * 4 + r;                    // lane src (q=0 group) holds row src
    lv0[r] = __shfl(ls0, src, 64);
    lv1[r] = __shfl(ls1, src, 64);
  }

  // ---- epilogue arena (aliases Pbuf, which is dead after the barrier) ----
  float* pub = smem_f;                       // [4 waves][64 lanes][24]
  float* Pl  = smem_f + 6144;                // [32][36] normalized P tile
  float* red = smem_f + 7296;                // [4 waves][128]

  __syncthreads();
  f32x4* mp = (f32x4*)(pub + (w * 64 + lane) * 24);
  mp[0] = o00; mp[1] = o01; mp[2] = o10; mp[3] = o11;
  mp[4] = lv0; mp[5] = lv1;
  __syncthreads();

  // parallel merge: wave w owns group w; ls0 for w<2, ls1 for w>=2.
  {
    int lsIdx = 4 + (w >> 1);
    const f32x4* p0 = (const f32x4*)(pub + lane * 24);
    f32x4 osum = p0[w];
    f32x4 lsum = p0[lsIdx];
#pragma unroll
    for (int ww = 1; ww < 4; ++ww) {
      const f32x4* pp = (const f32x4*)(pub + (ww * 64 + lane) * 24);
      f32x4 ov = pp[w], lv = pp[lsIdx];
#pragma unroll
      for (int r = 0; r < 4; ++r) { osum[r] += ov[r]; lsum[r] += lv[r]; }
    }
    int tile = w >> 1, colh = (w & 1) * 16;
#pragma unroll
    for (int r = 0; r < 4; ++r) {
      float p = osum[r] / lsum[r];
      int row = tile * 16 + q * 4 + r;
      P[(n * TV + row0 + row) * ICH + colh + m] = (__bf16)p;
      Pl[row * 36 + colh + m] = p;
    }
  }
  __syncthreads();

  // ---- fused BN stats: thread (c = t&63, rows w*8..w*8+7) 64ch dot.
  // Pl reads are wave-uniform b128 broadcasts (stride 36 -> 16B-aligned).
  int c = threadIdx.x & 63;
  float wr[ICH];
#pragma unroll
  for (int i = 0; i < ICH; ++i) wr[i] = Wt[c * ICH + i];
  float bc = bt[c];
  float sy = 0.f, sy2 = 0.f;
#pragma unroll
  for (int rr = 0; rr < 8; ++rr) {
    const f32x4* pr = (const f32x4*)(Pl + (w * 8 + rr) * 36);
    float y = bc;
#pragma unroll
    for (int u = 0; u < 8; ++u) {
      f32x4 pv = pr[u];
#pragma unroll
      for (int k = 0; k < 4; ++k) y = fmaf(wr[u * 4 + k], pv[k], y);
    }
    sy += y; sy2 += y * y;
  }
  red[w * 128 + c]      = sy;
  red[w * 128 + 64 + c] = sy2;
  __syncthreads();
  if (threadIdx.x < 128) {
    int t = threadIdx.x;
    float s = red[t] + red[128 + t] + red[256 + t] + red[384 + t];
    GSP[(size_t)blockIdx.x * 128 + t] = s;   // private slot, no atomics
  }
}

// ---------------------------------------------------------------------------
// K3: sum GSP[800][128] -> BN scale/shift SS, plus ChannelGate MLP -> GATE.
// 1 block, 256 threads (2-way split over the 800 slots).
// AVG lives in d_out (overwritten later by apply).
// ---------------------------------------------------------------------------
__global__ __launch_bounds__(256) void finalize_stats(
    const float* __restrict__ GSP, const float* __restrict__ gamma,
    const float* __restrict__ beta, const float* __restrict__ AVG,
    const float* __restrict__ W1, const float* __restrict__ b1,
    const float* __restrict__ W2, const float* __restrict__ b2,
    float* __restrict__ SS, float* __restrict__ GATE) {
  int t = threadIdx.x;
  __shared__ float acc2[2][128];
  __shared__ float shs[128];
  __shared__ float sh[NB][4];
  {
    int c = t & 127, half = t >> 7;
    float s = 0.f;
    for (int b = half * 400; b < half * 400 + 400; ++b)
      s += GSP[(size_t)b * 128 + c];
    acc2[half][c] = s;
  }
  __syncthreads();
  if (t < 128) shs[t] = acc2[0][t] + acc2[1][t];
  __syncthreads();
  if (t < 64) {
    int c = t;
    float mean = shs[c] * (1.f / (float)NTV);
    float var  = shs[64 + c] * (1.f / (float)NTV) - mean * mean;
    float scale = rsqrtf(var + 1e-5f) * gamma[c];
    SS[c] = scale;
    SS[64 + c] = beta[c] - mean * scale;
    int n = t >> 2, jj = t & 3;
    float h = b1[jj];
    for (int c2 = 0; c2 < CC; ++c2)
      h = fmaf(W1[jj * CC + c2], AVG[n * CC + c2], h);
    sh[n][jj] = fmaxf(h, 0.f);
  }
  __syncthreads();
#pragma unroll
  for (int u = 0; u < 4; ++u) {
    int idx = t * 4 + u;
    int n = idx >> 6, c = idx & 63;
    float g = b2[c];
#pragma unroll
    for (int jj = 0; jj < 4; ++jj) g = fmaf(W2[c * 4 + jj], sh[n][jj], g);
    GATE[idx] = 1.f / (1.f + __expf(-g));
  }
}

// ---------------------------------------------------------------------------
// K4: recompute y for 8 channels from bf16 P, apply BN + gate + residual.
// XCD-SWIZZLED: the 8 cg-blocks sharing a P tv-tile land on one XCD residue
// (P tile L2-resident across its 8 readers). Grid 832 (32 no-op).
// ---------------------------------------------------------------------------
__global__ __launch_bounds__(256) void apply_kernel(
    const __bf16* __restrict__ P, const float* __restrict__ Wt,
    const float* __restrict__ bt, const float* __restrict__ SS,
    const float* __restrict__ gate, const float* __restrict__ x,
    float* __restrict__ out) {
  int r = blockIdx.x & 7;
  int i = blockIdx.x >> 3;              // 0..103
  int cg = i & 7, h = i >> 3;           // h in 0..12
  int tb = r + 8 * h;
  if (tb >= 100) return;                // 32 no-op blocks

  int tvIdx = tb * 256 + threadIdx.x;
  int n = tvIdx / TV, tv = tvIdx % TV;

  float f[ICH];
  const bf16x8* pp = (const bf16x8*)(P + ((size_t)(n * TV + tv)) * ICH);
#pragma unroll
  for (int u = 0; u < 4; ++u) {
    bf16x8 v = pp[u];
#pragma unroll
    for (int j = 0; j < 8; ++j) f[u * 8 + j] = (float)v[j];
  }

#pragma unroll
  for (int j = 0; j < 8; ++j) {
    int c = cg * 8 + j;
    float y = bt[c];
#pragma unroll
    for (int ii = 0; ii < ICH; ++ii) y = fmaf(Wt[c * ICH + ii], f[ii], y);
    size_t idx = ((size_t)(n * CC + c)) * TV + tv;
    out[idx] = gate[n * CC + c] * fmaf(y, SS[c], SS[64 + c]) + x[idx];
  }
}

// ---------------------------------------------------------------------------
extern "C" void kernel_launch(void* const* d_in, const int* in_sizes, int n_in,
                              void* d_out, int out_size, void* d_ws, size_t ws_size,
                              hipStream_t stream) {
  const float* x     = (const float*)d_in[0];
  const float* Wv    = (const float*)d_in[1];
  const float* bv    = (const float*)d_in[2];
  const float* Wk    = (const float*)d_in[3];
  const float* bk    = (const float*)d_in[4];
  const float* Wq    = (const float*)d_in[5];
  const float* bq    = (const float*)d_in[6];
  const float* Wt    = (const float*)d_in[7];
  const float* bt    = (const float*)d_in[8];
  const float* gamma = (const float*)d_in[9];
  const float* beta  = (const float*)d_in[10];
  const float* W1    = (const float*)d_in[11];
  const float* b1    = (const float*)d_in[12];
  const float* W2    = (const float*)d_in[13];
  const float* b2    = (const float*)d_in[14];
  float* out = (float*)d_out;
  char* ws = (char*)d_ws;

  // workspace layout (bytes) — total ~7.0 MB
  const size_t E = 819200;                    // N*TV*ICH elements
  __bf16* Qb  = (__bf16*)(ws);                // 2E bytes
  __bf16* Kb  = (__bf16*)(ws + 2*E);          // 2E bytes
  __bf16* VTb = (__bf16*)(ws + 4*E);          // 2E bytes
  __bf16* Pb  = (__bf16*)(ws + 6*E);          // 2E bytes
  float*  GSP = (float*) (ws + 8*E);          // 409600 B per-block partials
  float*  SS  = (float*) (ws + 8*E + 409600); // 512 B
  float*  GATE= (float*) (ws + 8*E + 410112); // 4096 B
  float*  AVG = out;   // scratch: fully overwritten by apply_kernel

  proj_gate_kernel<<<1312, 256, 0, stream>>>(x, Wv, bv, Wk, bk, Wq, bq,
                                             Qb, Kb, VTb, AVG);
  attn_kernel<<<NB * 50, 256, 0, stream>>>(Qb, Kb, VTb, Pb, Wt, bt, GSP);
  finalize_stats<<<1, 256, 0, stream>>>(GSP, gamma, beta, AVG,
                                        W1, b1, W2, b2, SS, GATE);
  apply_kernel<<<832, 256, 0, stream>>>(Pb, Wt, bt, SS, GATE, x, out);
}

// Round 2
// 134.667 us; speedup vs baseline: 1.0502x; 1.0502x over previous
//
#include <hip/hip_runtime.h>
#include <hip/hip_bf16.h>
#include <math.h>

// Problem constants
#define NB   16      // batch
#define CC   64      // channels
#define ICH  32      // inter channels
#define TV   1600    // T*V = 64*25
#define NTV  (NB*TV) // 25600

typedef __bf16 bf16x8 __attribute__((ext_vector_type(8)));
typedef __bf16 bf16x4 __attribute__((ext_vector_type(4)));
typedef float  f32x4  __attribute__((ext_vector_type(4)));

// ---------------------------------------------------------------------------
// K1: 1x1 conv projections, p-split (12-way: 3 proj x 4 o-groups), XCD-
// SWIZZLED so all 12 blocks sharing an x-tile land on ONE XCD residue class.
// Proj blocks 0..1247 (48 no-op), gate blocks 1248..1311.
//  Qb = k_x [N,TV,32] (PRE-SCALED by log2e -> attn uses v_exp_f32 directly)
//  Kb = q_x [N,TV,32]   VTb = v_x^T [N,32,TV]   AVG -> workspace (read by K3)
// ---------------------------------------------------------------------------
__global__ __launch_bounds__(256) void proj_gate_kernel(
    const float* __restrict__ x,
    const float* __restrict__ Wv, const float* __restrict__ bv,
    const float* __restrict__ Wk, const float* __restrict__ bk,
    const float* __restrict__ Wq, const float* __restrict__ bq,
    __bf16* __restrict__ Qb, __bf16* __restrict__ Kb,
    __bf16* __restrict__ VTb, float* __restrict__ AVG) {
  if (blockIdx.x >= 1248) {
    // ---- ChannelGate phase 1: per-(n, c) mean over TV ----
    int b = blockIdx.x - 1248;
    int n = b >> 2, cq = b & 3;
    int c16 = threadIdx.x >> 4, l = threadIdx.x & 15;
    int c = cq * 16 + c16;
    const float4* xp = (const float4*)(x + ((size_t)n * CC + c) * TV) + l;
    float s = 0.f;
#pragma unroll
    for (int i = 0; i < 25; ++i) {
      float4 v = xp[i * 16];
      s += v.x + v.y + v.z + v.w;
    }
#pragma unroll
    for (int off = 8; off >= 1; off >>= 1) s += __shfl_down(s, off, 16);
    if (l == 0) AVG[n * CC + c] = s * (1.0f / (float)TV);
    return;
  }

  // XCD swizzle: XCD = blockIdx % 8; tile = r + 8g so all subs of a tile
  // share residue r -> same XCD.
  int r = blockIdx.x & 7;
  int i = blockIdx.x >> 3;               // 0..155
  int g = i / 12, sub = i % 12;          // sub = p*4 + og
  int tile = r + 8 * g;
  if (tile >= 100) return;               // 48 no-op blocks

  int p = sub >> 2, og = sub & 3;
  int ob = og * 8;
  int tvIdx = tile * 256 + threadIdx.x;  // 0..25599
  int n = tvIdx / TV, tv = tvIdx % TV;

  const float* W; const float* B;
  if (p == 0)      { W = Wv; B = bv; }
  else if (p == 1) { W = Wk; B = bk; }
  else             { W = Wq; B = bq; }

  float acc[8];
#pragma unroll
  for (int j = 0; j < 8; ++j) acc[j] = B[ob + j];

  const float* xp = x + (size_t)n * CC * TV + tv;
#pragma unroll 16
  for (int c = 0; c < CC; ++c) {
    float xc = xp[c * TV];
#pragma unroll
    for (int j = 0; j < 8; ++j)
      acc[j] = fmaf(W[(ob + j) * CC + c], xc, acc[j]);
  }

  if (p == 0) {                           // v_x -> transposed
#pragma unroll
    for (int j = 0; j < 8; ++j)
      VTb[(n * ICH + ob + j) * TV + tv] = (__bf16)acc[j];
  } else {
    if (p == 1) {                         // fold log2(e) into k_x: attention
#pragma unroll                            // scores become log2-domain, so the
      for (int j = 0; j < 8; ++j)         // attn kernel uses raw v_exp_f32
        acc[j] *= 1.4426950408889634f;
    }
    bf16x8 t;
#pragma unroll
    for (int j = 0; j < 8; ++j) t[j] = (__bf16)acc[j];
    int base = (n * TV + tv) * ICH + ob;
    if (p == 1) *(bf16x8*)(Qb + base) = t;   // k_x -> attention rows
    else        *(bf16x8*)(Kb + base) = t;   // q_x -> attention cols
  }
}

// ---------------------------------------------------------------------------
// K2: MFMA flash attention (bf16, 2 m-tiles/wave, XCD swizzle, K+V register
// pipelining) + fused BN-stats epilogue with 4-way parallel merge.
// QK^T computed SWAPPED (mfma(K,Q) -> P^T in C-regs): lane (q,m) holds 4
// CONSECUTIVE s-values of attention row m -> packed ds_write_b64 into the
// [row][s] Pbuf. exp via v_exp_f32 (log2e pre-folded into Qb).
// BN partials now written COLUMN-MAJOR: GSP[c*800 + block] so the consumer
// (apply_kernel, which needs only 16 of 128 columns) reads contiguous runs.
// Grid = NB*50 = 800. LDS 31,744 B.
// ---------------------------------------------------------------------------
__global__ __launch_bounds__(256) void attn_kernel(
    const __bf16* __restrict__ Qb, const __bf16* __restrict__ Kb,
    const __bf16* __restrict__ VTb, __bf16* __restrict__ P,
    const float* __restrict__ Wt, const float* __restrict__ bt,
    float* __restrict__ GSP) {
  __shared__ float smem_f[7936];             // 31,744 B union arena
  int b = blockIdx.x;
  int r8 = b & 7, qq = b >> 3;               // qq in [0,100)
  int n = r8 * 2 + (qq >= 50 ? 1 : 0);
  int rowTile = (qq >= 50) ? qq - 50 : qq;
  int row0 = rowTile * 32;

  int w = threadIdx.x >> 6;
  int lane = threadIdx.x & 63;
  int m = lane & 15, q = lane >> 4;

  // main-loop Pbuf: per wave 2 tiles x 16 x 72 bf16 = 2304 elem (4608 B)
  __bf16* Pw = (__bf16*)smem_f + w * 2304;

  const __bf16* Qn = Qb  + (size_t)n * TV * ICH;
  const __bf16* Kn = Kb  + (size_t)n * TV * ICH;
  const __bf16* Vn = VTb + (size_t)n * ICH * TV;

  bf16x8 aQ0 = *(const bf16x8*)(Qn + (row0 + m) * ICH + q * 8);
  bf16x8 aQ1 = *(const bf16x8*)(Qn + (row0 + 16 + m) * ICH + q * 8);

  f32x4 o00 = {0.f,0.f,0.f,0.f}, o01 = {0.f,0.f,0.f,0.f};
  f32x4 o10 = {0.f,0.f,0.f,0.f}, o11 = {0.f,0.f,0.f,0.f};
  float ls0 = 0.f, ls1 = 0.f;                // lane-local rowsum (row = m)
  const f32x4 zero = {0.f,0.f,0.f,0.f};

  // chunk offset for this wave, rotated per block so the extra (7th) chunk
  // (offset 0) moves between waves across blocks.
  int ow = (w + b) & 3;                      // offset residue; 0 -> 7 chunks
  int nch = (ow == 0) ? 7 : 6;

  // preload chunk 0's K fragments into registers
  bf16x8 bKc[4];
  {
    int s0 = ow * 64;
#pragma unroll
    for (int st = 0; st < 4; ++st)
      bKc[st] = *(const bf16x8*)(Kn + (s0 + st * 16 + m) * ICH + q * 8);
  }

  for (int j = 0; j < nch; ++j) {
    int s0 = (4 * j + ow) * 64;
    // ---- swapped QK^T: C = P^T tile, lane (q,m): col=m (attn row),
    //      rows = s-offset st*16 + q*4 + r (4 consecutive s per lane) ----
#pragma unroll
    for (int st = 0; st < 4; ++st) {
      f32x4 a0 = __builtin_amdgcn_mfma_f32_16x16x32_bf16(bKc[st], aQ0, zero, 0, 0, 0);
      f32x4 a1 = __builtin_amdgcn_mfma_f32_16x16x32_bf16(bKc[st], aQ1, zero, 0, 0, 0);
      bf16x4 t0, t1;
#pragma unroll
      for (int r = 0; r < 4; ++r) {
        float e0 = __builtin_amdgcn_exp2f(a0[r]); ls0 += e0; t0[r] = (__bf16)e0;
        float e1 = __builtin_amdgcn_exp2f(a1[r]); ls1 += e1; t1[r] = (__bf16)e1;
      }
      int off = m * 72 + st * 16 + q * 4;    // byte off m*144+st*32+q*8: 8B-aligned
      *(bf16x4*)(Pw + off)        = t0;      // one ds_write_b64 per st/tile
      *(bf16x4*)(Pw + 1152 + off) = t1;
    }
    // prefetch next chunk's K + this chunk's V BEFORE the wait
    int chn = 4 * (j + 1) + ow;
    int s0n = (chn < 25 ? chn : 0) * 64;       // clamped, wave-uniform
    bf16x8 bKn[4], pV[2][2];
#pragma unroll
    for (int st = 0; st < 4; ++st)
      bKn[st] = *(const bf16x8*)(Kn + (s0n + st * 16 + m) * ICH + q * 8);
#pragma unroll
    for (int kc = 0; kc < 2; ++kc)
#pragma unroll
      for (int ict = 0; ict < 2; ++ict)
        pV[kc][ict] = *(const bf16x8*)(Vn + (ict * 16 + m) * TV + s0 + kc * 32 + q * 8);
    // in-wave DS write->read ordering
    asm volatile("s_waitcnt lgkmcnt(0)" ::: "memory");
    // ---- P*V: 2 k-chunks of 32 s ----
#pragma unroll
    for (int kc = 0; kc < 2; ++kc) {
      bf16x8 aP0 = *(const bf16x8*)(Pw + m * 72 + kc * 32 + q * 8);
      bf16x8 aP1 = *(const bf16x8*)(Pw + 1152 + m * 72 + kc * 32 + q * 8);
      o00 = __builtin_amdgcn_mfma_f32_16x16x32_bf16(aP0, pV[kc][0], o00, 0, 0, 0);
      o10 = __builtin_amdgcn_mfma_f32_16x16x32_bf16(aP1, pV[kc][0], o10, 0, 0, 0);
      o01 = __builtin_amdgcn_mfma_f32_16x16x32_bf16(aP0, pV[kc][1], o01, 0, 0, 0);
      o11 = __builtin_amdgcn_mfma_f32_16x16x32_bf16(aP1, pV[kc][1], o11, 0, 0, 0);
    }
#pragma unroll
    for (int st = 0; st < 4; ++st) bKc[st] = bKn[st];
  }

  // row sums: lane (q,m) has the partial for row m over its q-subset of s;
  // sum the 4 q-lanes, then gather into the merge layout (row = q*4+r).
  ls0 += __shfl_xor(ls0, 16, 64); ls0 += __shfl_xor(ls0, 32, 64);
  ls1 += __shfl_xor(ls1, 16, 64); ls1 += __shfl_xor(ls1, 32, 64);
  f32x4 lv0, lv1;
#pragma unroll
  for (int r = 0; r < 4; ++r) {
    int src = q * 4 + r;                    // lane src (q=0 group) holds row src
    lv0[r] = __shfl(ls0, src, 64);
    lv1[r] = __shfl(ls1, src, 64);
  }

  // ---- epilogue arena (aliases Pbuf, which is dead after the barrier) ----
  float* pub = smem_f;                       // [4 waves][64 lanes][24]
  float* Pl  = smem_f + 6144;                // [32][36] normalized P tile
  float* red = smem_f + 7296;                // [4 waves][128]

  __syncthreads();
  f32x4* mp = (f32x4*)(pub + (w * 64 + lane) * 24);
  mp[0] = o00; mp[1] = o01; mp[2] = o10; mp[3] = o11;
  mp[4] = lv0; mp[5] = lv1;
  __syncthreads();

  // parallel merge: wave w owns group w; ls0 for w<2, ls1 for w>=2.
  {
    int lsIdx = 4 + (w >> 1);
    const f32x4* p0 = (const f32x4*)(pub + lane * 24);
    f32x4 osum = p0[w];
    f32x4 lsum = p0[lsIdx];
#pragma unroll
    for (int ww = 1; ww < 4; ++ww) {
      const f32x4* pp = (const f32x4*)(pub + (ww * 64 + lane) * 24);
      f32x4 ov = pp[w], lv = pp[lsIdx];
#pragma unroll
      for (int r = 0; r < 4; ++r) { osum[r] += ov[r]; lsum[r] += lv[r]; }
    }
    int tile = w >> 1, colh = (w & 1) * 16;
#pragma unroll
    for (int r = 0; r < 4; ++r) {
      float p = osum[r] / lsum[r];
      int row = tile * 16 + q * 4 + r;
      P[(n * TV + row0 + row) * ICH + colh + m] = (__bf16)p;
      Pl[row * 36 + colh + m] = p;
    }
  }
  __syncthreads();

  // ---- fused BN stats: thread (c = t&63, rows w*8..w*8+7) 64ch dot.
  // Pl reads are wave-uniform b128 broadcasts (stride 36 -> 16B-aligned).
  int c = threadIdx.x & 63;
  float wr[ICH];
#pragma unroll
  for (int i = 0; i < ICH; ++i) wr[i] = Wt[c * ICH + i];
  float bc = bt[c];
  float sy = 0.f, sy2 = 0.f;
#pragma unroll
  for (int rr = 0; rr < 8; ++rr) {
    const f32x4* pr = (const f32x4*)(Pl + (w * 8 + rr) * 36);
    float y = bc;
#pragma unroll
    for (int u = 0; u < 8; ++u) {
      f32x4 pv = pr[u];
#pragma unroll
      for (int k = 0; k < 4; ++k) y = fmaf(wr[u * 4 + k], pv[k], y);
    }
    sy += y; sy2 += y * y;
  }
  red[w * 128 + c]      = sy;
  red[w * 128 + 64 + c] = sy2;
  __syncthreads();
  if (threadIdx.x < 128) {
    int t = threadIdx.x;
    float s = red[t] + red[128 + t] + red[256 + t] + red[384 + t];
    GSP[(size_t)t * 800 + blockIdx.x] = s;   // COLUMN-MAJOR: consumer-contiguous
  }
}

// ---------------------------------------------------------------------------
// K3 (was K4): fused finalize + apply. Each block redundantly recomputes the
// 16 BN-stat column sums it needs (its 8 channels' sum-y / sum-y2 over the
// 800 GSP slots; column-major GSP -> coalesced 64 B runs, ~51 KB/block, L2)
// plus the ChannelGate MLP for its (n, 8ch) slice, then recomputes y from
// bf16 P and applies BN + gate + residual. Removes the grid-1 finalize
// dispatch (full-device bubble) from the DAG. XCD-SWIZZLED over P tv-tiles.
// Grid 832 (32 no-op).
// ---------------------------------------------------------------------------
__global__ __launch_bounds__(256) void apply_kernel(
    const __bf16* __restrict__ P, const float* __restrict__ Wt,
    const float* __restrict__ bt, const float* __restrict__ GSP,
    const float* __restrict__ gamma, const float* __restrict__ beta,
    const float* __restrict__ AVG,
    const float* __restrict__ W1, const float* __restrict__ b1,
    const float* __restrict__ W2, const float* __restrict__ b2,
    const float* __restrict__ x, float* __restrict__ out) {
  int r = blockIdx.x & 7;
  int i = blockIdx.x >> 3;              // 0..103
  int cg = i & 7, h = i >> 3;           // h in 0..12
  int tb = r + 8 * h;
  if (tb >= 100) return;                // 32 no-op blocks

  int tvIdx = tb * 256 + threadIdx.x;
  int n = tvIdx / TV, tv = tvIdx % TV;

  __shared__ float sstat[16];           // [0..7]=sum y, [8..15]=sum y^2
  __shared__ float sSS[16];             // [0..7]=scale, [8..15]=shift
  __shared__ float sG[8];               // gate for (n, cg*8..cg*8+7)

  // ---- Phase A: 16 threads/column sum 50 slots each (contiguous stride-16
  // runs within a column-major GSP row of 800) ----
  {
    int colid = threadIdx.x >> 4;       // 0..15
    int sub = threadIdx.x & 15;         // 0..15
    int c8 = colid & 7;
    int gc = (colid < 8) ? (cg * 8 + c8) : (64 + cg * 8 + c8);
    const float* gp = GSP + (size_t)gc * 800;
    float s = 0.f;
#pragma unroll
    for (int k = 0; k < 50; ++k) s += gp[sub + k * 16];
#pragma unroll
    for (int off = 8; off >= 1; off >>= 1) s += __shfl_down(s, off, 16);
    if (sub == 0) sstat[colid] = s;
  }
  __syncthreads();
  if (threadIdx.x < 8) {
    int c8 = threadIdx.x;
    int c = cg * 8 + c8;
    float mean = sstat[c8] * (1.f / (float)NTV);
    float var  = sstat[8 + c8] * (1.f / (float)NTV) - mean * mean;
    float scale = rsqrtf(var + 1e-5f) * gamma[c];
    sSS[c8] = scale;
    sSS[8 + c8] = beta[c] - mean * scale;
    // ChannelGate MLP for this n (redundant across the 8 lanes, tiny)
    float hh[4];
#pragma unroll
    for (int jj = 0; jj < 4; ++jj) {
      float hv = b1[jj];
      for (int c2 = 0; c2 < CC; ++c2)
        hv = fmaf(W1[jj * CC + c2], AVG[n * CC + c2], hv);
      hh[jj] = fmaxf(hv, 0.f);
    }
    float g = b2[c];
#pragma unroll
    for (int jj = 0; jj < 4; ++jj) g = fmaf(W2[c * 4 + jj], hh[jj], g);
    sG[c8] = 1.f / (1.f + __expf(-g));
  }
  __syncthreads();

  // ---- Phase B: recompute y for 8 channels from bf16 P, apply ----
  float f[ICH];
  const bf16x8* pp = (const bf16x8*)(P + ((size_t)(n * TV + tv)) * ICH);
#pragma unroll
  for (int u = 0; u < 4; ++u) {
    bf16x8 v = pp[u];
#pragma unroll
    for (int j = 0; j < 8; ++j) f[u * 8 + j] = (float)v[j];
  }

#pragma unroll
  for (int j = 0; j < 8; ++j) {
    int c = cg * 8 + j;
    float y = bt[c];
#pragma unroll
    for (int ii = 0; ii < ICH; ++ii) y = fmaf(Wt[c * ICH + ii], f[ii], y);
    size_t idx = ((size_t)(n * CC + c)) * TV + tv;
    out[idx] = sG[j] * fmaf(y, sSS[j], sSS[8 + j]) + x[idx];
  }
}

// ---------------------------------------------------------------------------
extern "C" void kernel_launch(void* const* d_in, const int* in_sizes, int n_in,
                              void* d_out, int out_size, void* d_ws, size_t ws_size,
                              hipStream_t stream) {
  const float* x     = (const float*)d_in[0];
  const float* Wv    = (const float*)d_in[1];
  const float* bv    = (const float*)d_in[2];
  const float* Wk    = (const float*)d_in[3];
  const float* bk    = (const float*)d_in[4];
  const float* Wq    = (const float*)d_in[5];
  const float* bq    = (const float*)d_in[6];
  const float* Wt    = (const float*)d_in[7];
  const float* bt    = (const float*)d_in[8];
  const float* gamma = (const float*)d_in[9];
  const float* beta  = (const float*)d_in[10];
  const float* W1    = (const float*)d_in[11];
  const float* b1    = (const float*)d_in[12];
  const float* W2    = (const float*)d_in[13];
  const float* b2    = (const float*)d_in[14];
  float* out = (float*)d_out;
  char* ws = (char*)d_ws;

  // workspace layout (bytes) — total ~7.0 MB
  const size_t E = 819200;                    // N*TV*ICH elements
  __bf16* Qb  = (__bf16*)(ws);                // 2E bytes
  __bf16* Kb  = (__bf16*)(ws + 2*E);          // 2E bytes
  __bf16* VTb = (__bf16*)(ws + 4*E);          // 2E bytes
  __bf16* Pb  = (__bf16*)(ws + 6*E);          // 2E bytes
  float*  GSP = (float*) (ws + 8*E);          // 409600 B column-major partials
  float*  AVG = (float*) (ws + 8*E + 409600); // 4096 B (NB*CC)

  proj_gate_kernel<<<1312, 256, 0, stream>>>(x, Wv, bv, Wk, bk, Wq, bq,
                                             Qb, Kb, VTb, AVG);
  attn_kernel<<<NB * 50, 256, 0, stream>>>(Qb, Kb, VTb, Pb, Wt, bt, GSP);
  apply_kernel<<<832, 256, 0, stream>>>(Pb, Wt, bt, GSP, gamma, beta, AVG,
                                        W1, b1, W2, b2, x, out);
}